// Round 10
// baseline (199.953 us; speedup 1.0000x reference)
//
#include <hip/hip_runtime.h>
#include <math.h>

// Problem constants: bs=64, n=16384, dx=128, dy=256
#define BS     64
#define NN     16384
#define DX     128
#define DY     256
#define ZDIM   (4 * DX)          // 512
#define NCHUNK 8
#define ROWS_PER_CHUNK (NN / NCHUNK)   // 2048

typedef float floatx4 __attribute__((ext_vector_type(4)));

// ---------------------------------------------------------------------------
// DIAGNOSTIC ROUND: byte-identical to R8 (111.5 us) EXCEPT stats_partial is
// launched TWICE (idempotent: same input -> same partials; output unchanged).
// dur2 = 2*K1 + T; with R8's K1 + T = 111.5 this yields the exact split
// K1 = dur2 - 111.5, T = 223 - dur2 — the rocprof table is blinded by the
// harness's 320us fill dispatches, so we make our own measurement.
// ---------------------------------------------------------------------------
__global__ __launch_bounds__(256) void stats_partial(
    const float* __restrict__ X, float* __restrict__ ws) {
    const int b = blockIdx.x;
    const int c = blockIdx.y;
    const int t = threadIdx.x;
    const int q = t & 31;    // column quad (cols 4q..4q+3)
    const int rg = t >> 5;   // row group 0..7 -> rows [rg*256, rg*256+256)

    const floatx4* __restrict__ Xt = (const floatx4*)(
        X + (size_t)b * NN * DX + (size_t)c * ROWS_PER_CHUNK * DX) +
        (size_t)rg * 256 * 32 + q;

    float s0 = 0.f, s1 = 0.f, s2 = 0.f, s3 = 0.f;       // sum
    float p0 = 0.f, p1 = 0.f, p2 = 0.f, p3 = 0.f;       // sum of squares
    float mn0 = INFINITY, mn1 = INFINITY, mn2 = INFINITY, mn3 = INFINITY;
    float mx0 = -INFINITY, mx1 = -INFINITY, mx2 = -INFINITY, mx3 = -INFINITY;

    #pragma unroll 8
    for (int s = 0; s < 256; ++s) {
        floatx4 v = __builtin_nontemporal_load(Xt + (size_t)s * 32);
        s0 += v.x; p0 += v.x * v.x; mn0 = fminf(mn0, v.x); mx0 = fmaxf(mx0, v.x);
        s1 += v.y; p1 += v.y * v.y; mn1 = fminf(mn1, v.y); mx1 = fmaxf(mx1, v.y);
        s2 += v.z; p2 += v.z * v.z; mn2 = fminf(mn2, v.z); mx2 = fmaxf(mx2, v.z);
        s3 += v.w; p3 += v.w * v.w; mn3 = fminf(mn3, v.w); mx3 = fmaxf(mx3, v.w);
    }

    // LDS: [group][quad][16: sum0..3, sumsq0..3, min0..3, max0..3]
    __shared__ float lds[8][32][16];
    float* L = lds[rg][q];
    L[0] = s0;  L[1] = s1;  L[2] = s2;  L[3] = s3;
    L[4] = p0;  L[5] = p1;  L[6] = p2;  L[7] = p3;
    L[8] = mn0; L[9] = mn1; L[10] = mn2; L[11] = mn3;
    L[12] = mx0; L[13] = mx1; L[14] = mx2; L[15] = mx3;
    __syncthreads();

    // Reduce across the 8 row-groups. 512 (comp,d) outputs, 2 per thread.
    for (int v = t; v < 512; v += 256) {
        const int comp = v >> 7;       // 0..3
        const int d = v & 127;
        const int qq = d >> 2;
        const int idx = comp * 4 + (d & 3);
        float r = lds[0][qq][idx];
        #pragma unroll
        for (int k = 1; k < 8; ++k) {
            const float x = lds[k][qq][idx];
            if (comp < 2)       r += x;
            else if (comp == 2) r = fminf(r, x);
            else                r = fmaxf(r, x);
        }
        ws[(((size_t)b * NCHUNK + c) * 4 + comp) * DX + d] = r;
    }
}

// ---------------------------------------------------------------------------
// Kernel 2 (fused tail): reduce 8 chunk partials -> z[512] -> out = z@W^T+b.
// Grid BS = 64 blocks, 256 threads. Identical to R8.
// ---------------------------------------------------------------------------
__global__ __launch_bounds__(256) void finalize(
    const float* __restrict__ ws, const float* __restrict__ W,
    const float* __restrict__ bias, float* __restrict__ out) {
    const int b = blockIdx.x;
    const int t = threadIdx.x;

    __shared__ float red[512];  // [sum(128), sumsq(128), min(128), max(128)]
    __shared__ float z[512];    // [mean, min, max, std]

    for (int v = t; v < 512; v += 256) {
        const int comp = v >> 7;
        const int d = v & 127;
        const float* __restrict__ p =
            ws + (((size_t)b * NCHUNK) * 4 + comp) * DX + d;
        float r = p[0];
        #pragma unroll
        for (int cc = 1; cc < NCHUNK; ++cc) {
            const float x = p[(size_t)cc * 512];
            if (comp < 2)       r += x;
            else if (comp == 2) r = fminf(r, x);
            else                r = fmaxf(r, x);
        }
        red[v] = r;
    }
    __syncthreads();

    if (t < DX) {
        const float s  = red[t];
        const float ss = red[DX + t];
        const float mean = s / (float)NN;
        const float var  = (ss - s * s / (float)NN) / (float)(NN - 1);
        z[t]            = mean;                    // mean
        z[DX + t]       = red[2 * DX + t];         // min
        z[2 * DX + t]   = red[3 * DX + t];         // max
        z[3 * DX + t]   = sqrtf(fmaxf(var, 0.f));  // std (ddof=1)
    }
    __syncthreads();

    // out[b][o] = bias[o] + dot(z, W[o][:])
    const int o = t;  // 256 outputs, 256 threads
    const float4* __restrict__ Wr = (const float4*)(W + (size_t)o * ZDIM);
    const float4* __restrict__ zz = (const float4*)z;
    float acc = bias[o];
    #pragma unroll 8
    for (int k = 0; k < ZDIM / 4; ++k) {
        const float4 w4 = Wr[k];
        const float4 zv = zz[k];
        acc += w4.x * zv.x + w4.y * zv.y + w4.z * zv.z + w4.w * zv.w;
    }
    out[(size_t)b * DY + o] = acc;
}

extern "C" void kernel_launch(void* const* d_in, const int* in_sizes, int n_in,
                              void* d_out, int out_size, void* d_ws, size_t ws_size,
                              hipStream_t stream) {
    const float* X    = (const float*)d_in[0];   // [64, 16384, 128] fp32
    const float* W    = (const float*)d_in[1];   // [256, 512] fp32
    const float* bias = (const float*)d_in[2];   // [256] fp32
    float* out        = (float*)d_out;           // [64, 256] fp32
    float* ws         = (float*)d_ws;            // partials: 1 MiB

    dim3 grid1(BS, NCHUNK);
    // DIAGNOSTIC: launch twice (idempotent) to measure K1 vs tail split.
    stats_partial<<<grid1, 256, 0, stream>>>(X, ws);
    stats_partial<<<grid1, 256, 0, stream>>>(X, ws);
    finalize<<<BS, 256, 0, stream>>>(ws, W, bias, out);
}

// Round 11
// 101.601 us; speedup vs baseline: 1.9680x; 1.9680x over previous
//
#include <hip/hip_runtime.h>
#include <math.h>

// Problem constants: bs=64, n=16384, dx=128, dy=256
#define BS     64
#define NN     16384
#define DX     128
#define DY     256
#define ZDIM   (4 * DX)          // 512
#define NCHUNK 8
#define ROWS_PER_CHUNK (NN / NCHUNK)   // 2048

typedef float floatx4 __attribute__((ext_vector_type(4)));

// ---------------------------------------------------------------------------
// Kernel 1: UNCHANGED from R8/R10 — measured ~88 us = 6.07 TB/s read
// (~96% of the 6.29 TB/s copy ceiling). At roofline; do not touch.
// ws[b][c][comp][d], comp: 0=sum 1=sumsq 2=min 3=max
// ---------------------------------------------------------------------------
__global__ __launch_bounds__(256) void stats_partial(
    const float* __restrict__ X, float* __restrict__ ws) {
    const int b = blockIdx.x;
    const int c = blockIdx.y;
    const int t = threadIdx.x;
    const int q = t & 31;    // column quad (cols 4q..4q+3)
    const int rg = t >> 5;   // row group 0..7 -> rows [rg*256, rg*256+256)

    const floatx4* __restrict__ Xt = (const floatx4*)(
        X + (size_t)b * NN * DX + (size_t)c * ROWS_PER_CHUNK * DX) +
        (size_t)rg * 256 * 32 + q;

    float s0 = 0.f, s1 = 0.f, s2 = 0.f, s3 = 0.f;       // sum
    float p0 = 0.f, p1 = 0.f, p2 = 0.f, p3 = 0.f;       // sum of squares
    float mn0 = INFINITY, mn1 = INFINITY, mn2 = INFINITY, mn3 = INFINITY;
    float mx0 = -INFINITY, mx1 = -INFINITY, mx2 = -INFINITY, mx3 = -INFINITY;

    #pragma unroll 8
    for (int s = 0; s < 256; ++s) {
        floatx4 v = __builtin_nontemporal_load(Xt + (size_t)s * 32);
        s0 += v.x; p0 += v.x * v.x; mn0 = fminf(mn0, v.x); mx0 = fmaxf(mx0, v.x);
        s1 += v.y; p1 += v.y * v.y; mn1 = fminf(mn1, v.y); mx1 = fmaxf(mx1, v.y);
        s2 += v.z; p2 += v.z * v.z; mn2 = fminf(mn2, v.z); mx2 = fmaxf(mx2, v.z);
        s3 += v.w; p3 += v.w * v.w; mn3 = fminf(mn3, v.w); mx3 = fmaxf(mx3, v.w);
    }

    // LDS: [group][quad][16: sum0..3, sumsq0..3, min0..3, max0..3]
    __shared__ float lds[8][32][16];
    float* L = lds[rg][q];
    L[0] = s0;  L[1] = s1;  L[2] = s2;  L[3] = s3;
    L[4] = p0;  L[5] = p1;  L[6] = p2;  L[7] = p3;
    L[8] = mn0; L[9] = mn1; L[10] = mn2; L[11] = mn3;
    L[12] = mx0; L[13] = mx1; L[14] = mx2; L[15] = mx3;
    __syncthreads();

    // Reduce across the 8 row-groups. 512 (comp,d) outputs, 2 per thread.
    for (int v = t; v < 512; v += 256) {
        const int comp = v >> 7;       // 0..3
        const int d = v & 127;
        const int qq = d >> 2;
        const int idx = comp * 4 + (d & 3);
        float r = lds[0][qq][idx];
        #pragma unroll
        for (int k = 1; k < 8; ++k) {
            const float x = lds[k][qq][idx];
            if (comp < 2)       r += x;
            else if (comp == 2) r = fminf(r, x);
            else                r = fmaxf(r, x);
        }
        ws[(((size_t)b * NCHUNK + c) * 4 + comp) * DX + d] = r;
    }
}

// ---------------------------------------------------------------------------
// Kernel 2 (tail, 4x parallel): grid (BS, 4) = 256 blocks, 256 threads.
// R10 diagnostic: old 64-block finalize = ~23 us (25% CU util, full-W per
// block, 128-iter serial dot). Now block (b, j): re-reduce the batch's 16 KB
// partials (4x duplicated, L2-hit), build z, compute output quarter
// o = j*64..j*64+63 with 4 lanes per output (128-length k-quarter dots,
// fixed-order shfl_xor reduce -> deterministic).
// ---------------------------------------------------------------------------
__global__ __launch_bounds__(256) void finalize(
    const float* __restrict__ ws, const float* __restrict__ W,
    const float* __restrict__ bias, float* __restrict__ out) {
    const int b = blockIdx.x;
    const int j = blockIdx.y;     // output quarter
    const int t = threadIdx.x;

    __shared__ float red[512];  // [sum(128), sumsq(128), min(128), max(128)]
    __shared__ float z[512];    // [mean, min, max, std]

    for (int v = t; v < 512; v += 256) {
        const int comp = v >> 7;
        const int d = v & 127;
        const float* __restrict__ p =
            ws + (((size_t)b * NCHUNK) * 4 + comp) * DX + d;
        float r = p[0];
        #pragma unroll
        for (int cc = 1; cc < NCHUNK; ++cc) {
            const float x = p[(size_t)cc * 512];
            if (comp < 2)       r += x;
            else if (comp == 2) r = fminf(r, x);
            else                r = fmaxf(r, x);
        }
        red[v] = r;
    }
    __syncthreads();

    if (t < DX) {
        const float s  = red[t];
        const float ss = red[DX + t];
        const float mean = s / (float)NN;
        const float var  = (ss - s * s / (float)NN) / (float)(NN - 1);
        z[t]            = mean;                    // mean
        z[DX + t]       = red[2 * DX + t];         // min
        z[2 * DX + t]   = red[3 * DX + t];         // max
        z[3 * DX + t]   = sqrtf(fmaxf(var, 0.f));  // std (ddof=1)
    }
    __syncthreads();

    // Output o = j*64 + (t>>2); lane kp = t&3 handles k in [kp*128, kp*128+128).
    const int o  = j * 64 + (t >> 2);
    const int kp = t & 3;
    const float4* __restrict__ Wr =
        (const float4*)(W + (size_t)o * ZDIM + (size_t)kp * 128);
    const float4* __restrict__ zz = (const float4*)z + kp * 32;
    float acc = 0.f;
    #pragma unroll 8
    for (int k = 0; k < 32; ++k) {
        const float4 w4 = Wr[k];
        const float4 zv = zz[k];
        acc += w4.x * zv.x + w4.y * zv.y + w4.z * zv.z + w4.w * zv.w;
    }
    // 4-lane fixed-order reduce: (kp0+kp1) + (kp2+kp3)
    acc += __shfl_xor(acc, 1, 64);
    acc += __shfl_xor(acc, 2, 64);
    if (kp == 0) out[(size_t)b * DY + o] = acc + bias[o];
}

extern "C" void kernel_launch(void* const* d_in, const int* in_sizes, int n_in,
                              void* d_out, int out_size, void* d_ws, size_t ws_size,
                              hipStream_t stream) {
    const float* X    = (const float*)d_in[0];   // [64, 16384, 128] fp32
    const float* W    = (const float*)d_in[1];   // [256, 512] fp32
    const float* bias = (const float*)d_in[2];   // [256] fp32
    float* out        = (float*)d_out;           // [64, 256] fp32
    float* ws         = (float*)d_ws;            // partials: 1 MiB

    dim3 grid1(BS, NCHUNK);
    stats_partial<<<grid1, 256, 0, stream>>>(X, ws);
    dim3 grid2(BS, 4);
    finalize<<<grid2, 256, 0, stream>>>(ws, W, bias, out);
}

// Round 12
// 101.596 us; speedup vs baseline: 1.9681x; 1.0001x over previous
//
#include <hip/hip_runtime.h>
#include <math.h>

// Problem constants: bs=64, n=16384, dx=128, dy=256
#define BS     64
#define NN     16384
#define DX     128
#define DY     256
#define ZDIM   (4 * DX)          // 512
#define NCHUNK 8
#define ROWS_PER_CHUNK (NN / NCHUNK)   // 2048

typedef float floatx4 __attribute__((ext_vector_type(4)));

// ---------------------------------------------------------------------------
// Kernel 1: UNCHANGED from R8/R10/R11 — measured ~88 us = 6.07 TB/s read
// (~96% of the 6.29 TB/s copy ceiling). At roofline; frozen.
// ws[b][c][comp][d], comp: 0=sum 1=sumsq 2=min 3=max
// ---------------------------------------------------------------------------
__global__ __launch_bounds__(256) void stats_partial(
    const float* __restrict__ X, float* __restrict__ ws) {
    const int b = blockIdx.x;
    const int c = blockIdx.y;
    const int t = threadIdx.x;
    const int q = t & 31;    // column quad (cols 4q..4q+3)
    const int rg = t >> 5;   // row group 0..7 -> rows [rg*256, rg*256+256)

    const floatx4* __restrict__ Xt = (const floatx4*)(
        X + (size_t)b * NN * DX + (size_t)c * ROWS_PER_CHUNK * DX) +
        (size_t)rg * 256 * 32 + q;

    float s0 = 0.f, s1 = 0.f, s2 = 0.f, s3 = 0.f;       // sum
    float p0 = 0.f, p1 = 0.f, p2 = 0.f, p3 = 0.f;       // sum of squares
    float mn0 = INFINITY, mn1 = INFINITY, mn2 = INFINITY, mn3 = INFINITY;
    float mx0 = -INFINITY, mx1 = -INFINITY, mx2 = -INFINITY, mx3 = -INFINITY;

    #pragma unroll 8
    for (int s = 0; s < 256; ++s) {
        floatx4 v = __builtin_nontemporal_load(Xt + (size_t)s * 32);
        s0 += v.x; p0 += v.x * v.x; mn0 = fminf(mn0, v.x); mx0 = fmaxf(mx0, v.x);
        s1 += v.y; p1 += v.y * v.y; mn1 = fminf(mn1, v.y); mx1 = fmaxf(mx1, v.y);
        s2 += v.z; p2 += v.z * v.z; mn2 = fminf(mn2, v.z); mx2 = fmaxf(mx2, v.z);
        s3 += v.w; p3 += v.w * v.w; mn3 = fminf(mn3, v.w); mx3 = fmaxf(mx3, v.w);
    }

    // LDS: [group][quad][16: sum0..3, sumsq0..3, min0..3, max0..3]
    __shared__ float lds[8][32][16];
    float* L = lds[rg][q];
    L[0] = s0;  L[1] = s1;  L[2] = s2;  L[3] = s3;
    L[4] = p0;  L[5] = p1;  L[6] = p2;  L[7] = p3;
    L[8] = mn0; L[9] = mn1; L[10] = mn2; L[11] = mn3;
    L[12] = mx0; L[13] = mx1; L[14] = mx2; L[15] = mx3;
    __syncthreads();

    // Reduce across the 8 row-groups. 512 (comp,d) outputs, 2 per thread.
    for (int v = t; v < 512; v += 256) {
        const int comp = v >> 7;       // 0..3
        const int d = v & 127;
        const int qq = d >> 2;
        const int idx = comp * 4 + (d & 3);
        float r = lds[0][qq][idx];
        #pragma unroll
        for (int k = 1; k < 8; ++k) {
            const float x = lds[k][qq][idx];
            if (comp < 2)       r += x;
            else if (comp == 2) r = fminf(r, x);
            else                r = fmaxf(r, x);
        }
        ws[(((size_t)b * NCHUNK + c) * 4 + comp) * DX + d] = r;
    }
}

// ---------------------------------------------------------------------------
// Kernel 2 (tail): grid (BS, 4) = 256 blocks, 256 threads — R11 structure.
// NEW: the block's W fragment (32 float4/thread = its output-quarter slice)
// and bias are preloaded into registers AT ENTRY, so their L2/HBM latency
// overlaps the reduce phase instead of serializing after the barrier
// (1 block/CU, 4 waves — nothing else hides it).
// ---------------------------------------------------------------------------
__global__ __launch_bounds__(256) void finalize(
    const float* __restrict__ ws, const float* __restrict__ W,
    const float* __restrict__ bias, float* __restrict__ out) {
    const int b = blockIdx.x;
    const int j = blockIdx.y;     // output quarter
    const int t = threadIdx.x;

    // Output o = j*64 + (t>>2); lane kp = t&3 owns k in [kp*128, kp*128+128).
    const int o  = j * 64 + (t >> 2);
    const int kp = t & 3;

    // ---- phase 0: issue W + bias loads immediately (latency hoist) ----
    const float4* __restrict__ Wr =
        (const float4*)(W + (size_t)o * ZDIM + (size_t)kp * 128);
    float4 wreg[32];
    #pragma unroll
    for (int k = 0; k < 32; ++k) wreg[k] = Wr[k];
    const float bo = bias[o];

    __shared__ float red[512];  // [sum(128), sumsq(128), min(128), max(128)]
    __shared__ float z[512];    // [mean, min, max, std]

    for (int v = t; v < 512; v += 256) {
        const int comp = v >> 7;
        const int d = v & 127;
        const float* __restrict__ p =
            ws + (((size_t)b * NCHUNK) * 4 + comp) * DX + d;
        float r = p[0];
        #pragma unroll
        for (int cc = 1; cc < NCHUNK; ++cc) {
            const float x = p[(size_t)cc * 512];
            if (comp < 2)       r += x;
            else if (comp == 2) r = fminf(r, x);
            else                r = fmaxf(r, x);
        }
        red[v] = r;
    }
    __syncthreads();

    if (t < DX) {
        const float s  = red[t];
        const float ss = red[DX + t];
        const float mean = s / (float)NN;
        const float var  = (ss - s * s / (float)NN) / (float)(NN - 1);
        z[t]            = mean;                    // mean
        z[DX + t]       = red[2 * DX + t];         // min
        z[2 * DX + t]   = red[3 * DX + t];         // max
        z[3 * DX + t]   = sqrtf(fmaxf(var, 0.f));  // std (ddof=1)
    }
    __syncthreads();

    const float4* __restrict__ zz = (const float4*)z + kp * 32;
    float acc = 0.f;
    #pragma unroll
    for (int k = 0; k < 32; ++k) {
        const float4 w4 = wreg[k];
        const float4 zv = zz[k];
        acc += w4.x * zv.x + w4.y * zv.y + w4.z * zv.z + w4.w * zv.w;
    }
    // 4-lane fixed-order reduce: (kp0+kp1) + (kp2+kp3)
    acc += __shfl_xor(acc, 1, 64);
    acc += __shfl_xor(acc, 2, 64);
    if (kp == 0) out[(size_t)b * DY + o] = acc + bo;
}

extern "C" void kernel_launch(void* const* d_in, const int* in_sizes, int n_in,
                              void* d_out, int out_size, void* d_ws, size_t ws_size,
                              hipStream_t stream) {
    const float* X    = (const float*)d_in[0];   // [64, 16384, 128] fp32
    const float* W    = (const float*)d_in[1];   // [256, 512] fp32
    const float* bias = (const float*)d_in[2];   // [256] fp32
    float* out        = (float*)d_out;           // [64, 256] fp32
    float* ws         = (float*)d_ws;            // partials: 1 MiB

    dim3 grid1(BS, NCHUNK);
    stats_partial<<<grid1, 256, 0, stream>>>(X, ws);
    dim3 grid2(BS, 4);
    finalize<<<grid2, 256, 0, stream>>>(ws, W, bias, out);
}